// Round 1
// baseline (130.914 us; speedup 1.0000x reference)
//
#include <hip/hip_runtime.h>

// YOLO decode: 3 scales, B=128, 45 ch = 3 anchors x (iou, dx, dy, dw, dh, 10 cls)
// Output: boxes [NTOT,6] fp32 then mask [NTOT] as 0/1 fp32.
// Round 5: + __expf (fast exp), 16B-block XOR swizzle on LDS staging
// (16-way ds_write conflict -> ~2-way), nontemporal loads/stores (pure
// streaming, no reuse -> don't thrash 32MB L2).

typedef float f4 __attribute__((ext_vector_type(4)));
typedef float f2 __attribute__((ext_vector_type(2)));

constexpr long N13 = 128L * 13 * 13 * 3;   //   64896
constexpr long N26 = 128L * 26 * 26 * 3;   //  259584
constexpr long N52 = 128L * 52 * 52 * 3;   // 1038336
constexpr long NTOT = N13 + N26 + N52;     // 1362816

constexpr int BLOCK = 192;                  // 3 waves: one per anchor
constexpr int GC52 = 128 * (52 * 52 / 4);   // 86528 = 64*1352
constexpr int GC26 = 128 * (26 * 26 / 4);   // 21632 = 64*338
constexpr int B52 = GC52 / 64;              // 1352
constexpr int B26 = GC26 / 64;              // 338
constexpr int B13 = (int)N13 / BLOCK;       // 338 (exact)

// XOR-swizzle of 16B-block index: breaks the 72-word per-lane stride
// (16-way bank conflict) down to ~2-way. Bijective within any 8-block
// group; both sbox (1152 blocks) and smask (192 blocks) are multiples of 8.
__device__ __forceinline__ int swz(int b16) { return b16 ^ ((b16 >> 3) & 7); }

// ---- vectorized path: wave = anchor, lane = global chunk (4 cells) ----
template <int H, int STRIDE, long ROWOFF>
__device__ __forceinline__ void decode_vec_lds(const float* __restrict__ o,
                                               const float* __restrict__ anc,
                                               float thresh,
                                               float* __restrict__ out, int blk)
{
    constexpr int hw = H * H;
    constexpr int C4 = hw / 4;

    __shared__ float sbox[768 * 6];   // 18 KB: block's 768 output rows (swizzled)
    __shared__ float smask[768];      //  3 KB (swizzled)

    const int lane = threadIdx.x & 63;
    const int a    = threadIdx.x >> 6;        // 0..2 (wave id = anchor)
    const int gc0  = blk * 64;
    const int gc   = gc0 + lane;              // global chunk id
    const int b    = gc / C4;
    const int chunk = gc % C4;

    const f4* base = (const f4*)o + (long)(b * 45 + a * 15) * C4 + chunk;

    f4 v[15];
#pragma unroll
    for (int j = 0; j < 15; ++j)
        v[j] = __builtin_nontemporal_load(base + (long)j * C4);  // contiguous/wave

    const float2 A = ((const float2*)anc)[a];

    int cell0 = chunk * 4;
    int x = cell0 % H;
    int y = cell0 / H;
    const int lr = lane * 12 + a;             // local row for i=0

#pragma unroll
    for (int i = 0; i < 4; ++i) {
        float iou = v[0][i];
        float px = ((float)x + v[1][i]) * (float)STRIDE;
        float py = ((float)y + v[2][i]) * (float)STRIDE;
        float pw = A.x * __expf(v[3][i]);
        float ph = A.y * __expf(v[4][i]);

        int kind = 0;
        float best = v[5][i];
#pragma unroll
        for (int c = 1; c < 10; ++c)
            if (v[5 + c][i] > best) { best = v[5 + c][i]; kind = c; }

        const int row = lr + i * 3;
        const int W = row * 6;
        // three float2 pieces; each is even-word-aligned so it sits inside
        // one 16B block -> safe to swizzle at block granularity
        {
            int w0 = W;     int p0 = swz(w0 >> 2) * 4 + (w0 & 3);
            *(f2*)&sbox[p0] = (f2){iou, px - 0.5f * pw};
            int w1 = W + 2; int p1 = swz(w1 >> 2) * 4 + (w1 & 3);
            *(f2*)&sbox[p1] = (f2){py - 0.5f * ph, px + 0.5f * pw};
            int w2 = W + 4; int p2 = swz(w2 >> 2) * 4 + (w2 & 3);
            *(f2*)&sbox[p2] = (f2){py + 0.5f * ph, (float)kind};
        }
        {
            int pm = swz(row >> 2) * 4 + (row & 3);
            smask[pm] = (iou > thresh) ? 1.0f : 0.0f;
        }

        if (++x == H) { x = 0; ++y; }
    }

    __syncthreads();

    // boxes: 1152 float4, contiguous in global, 6 per thread (same swizzle on read)
    const long row0 = ROWOFF + (long)gc0 * 12;
    f4* ob = (f4*)(out + row0 * 6);
#pragma unroll
    for (int k = 0; k < 6; ++k) {
        const int B = (int)threadIdx.x + k * BLOCK;
        __builtin_nontemporal_store(*(const f4*)&sbox[swz(B) * 4], ob + B);
    }

    // mask: 192 float4, contiguous, 1 per thread
    f4* om = (f4*)(out + 6 * NTOT + row0);
    __builtin_nontemporal_store(*(const f4*)&smask[swz((int)threadIdx.x) * 4],
                                om + (int)threadIdx.x);
}

// ---- scalar path (H=13: hw=169, not 16B-alignable; 4.8% of slots) ----
template <int H, int STRIDE, long ROWOFF>
__device__ __forceinline__ void decode_scalar(const float* __restrict__ o,
                                              const float* __restrict__ anc,
                                              float thresh,
                                              float* __restrict__ out, int tid)
{
    constexpr int hw = H * H;

    int a = tid % 3;
    int cell = tid / 3;
    int x = (cell % hw) % H;
    int y = (cell % hw) / H;
    int b = cell / hw;

    const float* p = o + (b * 45 + a * 15) * hw + y * H + x;

    float v[15];
#pragma unroll
    for (int j = 0; j < 15; ++j) v[j] = __builtin_nontemporal_load(p + j * hw);

    float iou = v[0];
    float px = ((float)x + v[1]) * (float)STRIDE;
    float py = ((float)y + v[2]) * (float)STRIDE;
    float2 A = ((const float2*)anc)[a];
    float pw = A.x * __expf(v[3]);
    float ph = A.y * __expf(v[4]);

    int kind = 0;
    float best = v[5];
#pragma unroll
    for (int c = 1; c < 10; ++c)
        if (v[5 + c] > best) { best = v[5 + c]; kind = c; }

    long row = ROWOFF + tid;
    float* orow = out + row * 6;
    __builtin_nontemporal_store((f2){iou, px - 0.5f * pw}, (f2*)orow);
    __builtin_nontemporal_store((f2){py - 0.5f * ph, px + 0.5f * pw}, (f2*)(orow + 2));
    __builtin_nontemporal_store((f2){py + 0.5f * ph, (float)kind}, (f2*)(orow + 4));
    __builtin_nontemporal_store((iou > thresh) ? 1.0f : 0.0f, out + 6 * NTOT + row);
}

__global__ __launch_bounds__(BLOCK) void decode_all(
    const float* __restrict__ o13, const float* __restrict__ o26,
    const float* __restrict__ o52, const float* __restrict__ a13,
    const float* __restrict__ a26, const float* __restrict__ a52,
    const float* __restrict__ thr, float* __restrict__ out)
{
    const float thresh = *thr;
    int blk = blockIdx.x;
    if (blk < B52) {
        decode_vec_lds<52, 8, N13 + N26>(o52, a52, thresh, out, blk);
    } else if (blk < B52 + B26) {
        decode_vec_lds<26, 16, N13>(o26, a26, thresh, out, blk - B52);
    } else {
        decode_scalar<13, 32, 0L>(o13, a13, thresh, out,
                                  (blk - B52 - B26) * BLOCK + (int)threadIdx.x);
    }
}

extern "C" void kernel_launch(void* const* d_in, const int* in_sizes, int n_in,
                              void* d_out, int out_size, void* d_ws, size_t ws_size,
                              hipStream_t stream) {
    const float* o13 = (const float*)d_in[0];
    const float* o26 = (const float*)d_in[1];
    const float* o52 = (const float*)d_in[2];
    const float* a13 = (const float*)d_in[3];
    const float* a26 = (const float*)d_in[4];
    const float* a52 = (const float*)d_in[5];
    const float* thr = (const float*)d_in[6];
    float* out = (float*)d_out;

    decode_all<<<B52 + B26 + B13, BLOCK, 0, stream>>>(o13, o26, o52, a13, a26, a52, thr, out);
}